// Round 4
// baseline (694.798 us; speedup 1.0000x reference)
//
#include <hip/hip_runtime.h>

// EM routing (matrix capsules), B=16,H=6,W=6,KH=KW=3,I=32,O=32,A=4, ITERATIONS=2.
//
// R4: single fused kernel, block = site (576 x 256). No workspace, no grid sync.
//  Phase 1: block streams its 576KB votes tile (coalesced float4), computes
//           M-step-1 moments, mu1 / 0.5/sig1 / base tables -> LDS.
//  Phase 2: BARRIER-FREE. Wave wv owns i = wv*8..wv*8+7. Lane l owns o=l&31,
//           kk in {h,h+2,h+4,h+6,8} (h=l>>5). Rows loaded from global (64B/lane
//           coalesced; pass-B reload is L2-warm). LSE = 6 shfl. Moments in regs.
//  Phase 3: in-block fold (shfl + 2 LDS hops) + finalize mu2/sig2/a_j2.
// Barriers per block: ~6 (R1 monolith: ~190). Votes read exactly 2x from HBM.
// Fixed harness overhead (~320us: 1.33GB ws poison + 340MB input restore) is
// out of scope; kernel target = two-pass HBM floor (~110us) + imbalance tail.

#define KKc 9
#define NIc 32
#define NOc 32
#define NAc 16
#define KIc 288    // KKc*NIc
#define NPc 512    // NOc*NAc
#define NSITE 576
#define EPSf 1e-7f
#define TWO_PIf 6.28318530717958647692f

__global__ __launch_bounds__(256, 3)
void em_fused(const float* __restrict__ votes, const float* __restrict__ acts_in,
              const float* __restrict__ beta_a, const float* __restrict__ beta_u,
              float* __restrict__ out)
{
  const int site = blockIdx.x;
  const int t    = threadIdx.x;

  __shared__ float s_act[KIc];
  __shared__ float s_mu[NPc];
  __shared__ float s_is[NPc];
  __shared__ float s_m1v[NPc];
  __shared__ float s_m1q[NPc];
  __shared__ float s_base[NOc];
  __shared__ float s_red[4];
  __shared__ float s_scr[4224 + 1056];   // s_p[33*128] then s_M[33*32]

  // ---------- phase 0: acts + sumR1 ----------
  s_act[t] = acts_in[site * KIc + t];
  if (t < 32) s_act[256 + t] = acts_in[site * KIc + 256 + t];
  __syncthreads();
  {
    float v = fmaf(0.8f, s_act[t], 0.2f);
    if (t < 32) v += fmaf(0.8f, s_act[256 + t], 0.2f);
#pragma unroll
    for (int off = 32; off; off >>= 1) v += __shfl_down(v, off, 64);
    if ((t & 63) == 0) s_red[t >> 6] = v;
  }
  __syncthreads();
  const float sumR1 = (s_red[0] + s_red[1] + s_red[2] + s_red[3]) * 0.03125f;

  // ---------- phase 1: M-step-1 moments + tables ----------
  {
    const int c  = t & 127;     // float4 column
    const int rr = t >> 7;      // row parity
    const float4* vb = reinterpret_cast<const float4*>(votes) + (size_t)site * (KIc * 128) + c;
    float pv0 = 0.f, pv1 = 0.f, pv2 = 0.f, pv3 = 0.f;
    float pq0 = 0.f, pq1 = 0.f, pq2 = 0.f, pq3 = 0.f;
#pragma unroll 8
    for (int k = 0; k < 144; ++k) {
      const int ki = rr + 2 * k;
      const float r = fmaf(0.8f, s_act[ki], 0.2f) * 0.03125f;
      const float4 x = vb[(size_t)ki * 128];
      pv0 = fmaf(r, x.x, pv0); pq0 = fmaf(r, x.x * x.x, pq0);
      pv1 = fmaf(r, x.y, pv1); pq1 = fmaf(r, x.y * x.y, pq1);
      pv2 = fmaf(r, x.z, pv2); pq2 = fmaf(r, x.z * x.z, pq2);
      pv3 = fmaf(r, x.w, pv3); pq3 = fmaf(r, x.w * x.w, pq3);
    }
    if (t >= 128) {
      float* f = s_scr + (size_t)(t - 128) * 8;
      f[0] = pv0; f[1] = pv1; f[2] = pv2; f[3] = pv3;
      f[4] = pq0; f[5] = pq1; f[6] = pq2; f[7] = pq3;
    }
    __syncthreads();
    if (t < 128) {
      const float* f = s_scr + (size_t)t * 8;
      pv0 += f[0]; pv1 += f[1]; pv2 += f[2]; pv3 += f[3];
      pq0 += f[4]; pq1 += f[5]; pq2 += f[6]; pq3 += f[7];

      const float sR1e = sumR1 + EPSf, sR1x = sumR1 + 2.f * EPSf;
      const float mu0 = pv0 / sR1e, mu1 = pv1 / sR1e, mu2 = pv2 / sR1e, mu3 = pv3 / sR1e;
      const float sg0 = fmaxf((pq0 - mu0 * mu0 * sR1x) / sR1e, 0.f);
      const float sg1 = fmaxf((pq1 - mu1 * mu1 * sR1x) / sR1e, 0.f);
      const float sg2 = fmaxf((pq2 - mu2 * mu2 * sR1x) / sR1e, 0.f);
      const float sg3 = fmaxf((pq3 - mu3 * mu3 * sR1x) / sR1e, 0.f);

      const int b = t * 4;
      s_mu[b] = mu0; s_mu[b + 1] = mu1; s_mu[b + 2] = mu2; s_mu[b + 3] = mu3;
      s_is[b] = 0.5f / sg0; s_is[b + 1] = 0.5f / sg1; s_is[b + 2] = 0.5f / sg2; s_is[b + 3] = 0.5f / sg3;
      s_m1v[b] = pv0; s_m1v[b + 1] = pv1; s_m1v[b + 2] = pv2; s_m1v[b + 3] = pv3;
      s_m1q[b] = pq0; s_m1q[b + 1] = pq1; s_m1q[b + 2] = pq2; s_m1q[b + 3] = pq3;

      const int o = t >> 2;
      const float bu = beta_u[o];
      float lt = logf(TWO_PIf * sg0 + EPSf) + logf(TWO_PIf * sg1 + EPSf)
               + logf(TWO_PIf * sg2 + EPSf) + logf(TWO_PIf * sg3 + EPSf);
      float ch = (4.f * bu - 0.5f * (logf(sg0 + EPSf) + logf(sg1 + EPSf)
                                   + logf(sg2 + EPSf) + logf(sg3 + EPSf))) * sumR1;
      ch += __shfl_xor(ch, 1, 64); ch += __shfl_xor(ch, 2, 64);
      lt += __shfl_xor(lt, 1, 64); lt += __shfl_xor(lt, 2, 64);
      if ((t & 3) == 0) {
        // inv_temp (it=0) = 0.01*(1-0.95) = 0.0005
        const float aj = 1.f / (1.f + expf(-(0.0005f * (beta_a[o] - ch))));
        s_base[o] = logf(aj + EPSf) - lt;
      }
    }
    __syncthreads();
  }

  // ---------- phase 2: barrier-free E-step + M-step-2 moments ----------
  const int wv = t >> 6, l = t & 63, o = l & 31, h = l >> 5;
  float mu[16], is[16];
#pragma unroll
  for (int a = 0; a < 16; ++a) { mu[a] = s_mu[o * 16 + a]; is[a] = s_is[o * 16 + a]; }
  const float lbase = s_base[o];
  const bool  v5    = (h == 0);   // 5th row (kk=8) owned by lower half only

  float accv[16], accq[16], accw = 0.f;
#pragma unroll
  for (int a = 0; a < 16; ++a) { accv[a] = 0.f; accq[a] = 0.f; }

  const float* vsb = votes + (size_t)site * (KIc * NPc) + o * NAc;

  for (int jj = 0; jj < 8; ++jj) {
    const int i = wv * 8 + jj;
    float lp[5];
    // pass A: log-probabilities for this lane's rows
#pragma unroll
    for (int r = 0; r < 5; ++r) {
      const int kk = (r < 4) ? (h + 2 * r) : 8;
      const float4* p4 = reinterpret_cast<const float4*>(vsb + (size_t)(kk * NIc + i) * NPc);
      float acc = 0.f;
#pragma unroll
      for (int j = 0; j < 4; ++j) {
        const float4 x = p4[j];
        float d;
        d = x.x - mu[4 * j];     acc = fmaf(d * d, is[4 * j],     acc);
        d = x.y - mu[4 * j + 1]; acc = fmaf(d * d, is[4 * j + 1], acc);
        d = x.z - mu[4 * j + 2]; acc = fmaf(d * d, is[4 * j + 2], acc);
        d = x.w - mu[4 * j + 3]; acc = fmaf(d * d, is[4 * j + 3], acc);
      }
      lp[r] = acc;
    }
    // wave logsumexp over all 288 rows (shfl only)
    float mn = fminf(fminf(lp[0], lp[1]), fminf(lp[2], lp[3]));
    if (v5) mn = fminf(mn, lp[4]);
    float lnx = lbase - mn;
#pragma unroll
    for (int off = 32; off; off >>= 1) lnx = fmaxf(lnx, __shfl_xor(lnx, off, 64));
    float e = expf(lbase - lp[0] - lnx) + expf(lbase - lp[1] - lnx)
            + expf(lbase - lp[2] - lnx) + expf(lbase - lp[3] - lnx);
    if (v5) e += expf(lbase - lp[4] - lnx);
#pragma unroll
    for (int off = 32; off; off >>= 1) e += __shfl_xor(e, off, 64);
    const float logden = lnx + logf(e);
    const float sb = lbase - logden;

    // pass B: weights + moments (reload is L2/L1-warm)
#pragma unroll
    for (int r = 0; r < 5; ++r) {
      const int kk = (r < 4) ? (h + 2 * r) : 8;
      float w = expf(sb - lp[r]) * (s_act[kk * NIc + i] * 0.8f);
      if (r == 4 && !v5) w = 0.f;
      accw += w;
      const float4* p4 = reinterpret_cast<const float4*>(vsb + (size_t)(kk * NIc + i) * NPc);
#pragma unroll
      for (int j = 0; j < 4; ++j) {
        const float4 x = p4[j];
        accv[4 * j]     = fmaf(w, x.x, accv[4 * j]);     accq[4 * j]     = fmaf(w, x.x * x.x, accq[4 * j]);
        accv[4 * j + 1] = fmaf(w, x.y, accv[4 * j + 1]); accq[4 * j + 1] = fmaf(w, x.y * x.y, accq[4 * j + 1]);
        accv[4 * j + 2] = fmaf(w, x.z, accv[4 * j + 2]); accq[4 * j + 2] = fmaf(w, x.z * x.z, accq[4 * j + 2]);
        accv[4 * j + 3] = fmaf(w, x.w, accv[4 * j + 3]); accq[4 * j + 3] = fmaf(w, x.w * x.w, accq[4 * j + 3]);
      }
    }
  }

  // ---------- phase 3: fold + finalize ----------
  accw += __shfl_xor(accw, 32, 64);
#pragma unroll
  for (int a = 0; a < 16; ++a) {
    accv[a] += __shfl_xor(accv[a], 32, 64);
    accq[a] += __shfl_xor(accq[a], 32, 64);
  }
  float* s_p = s_scr;
  if (l < 32) {
#pragma unroll
    for (int a = 0; a < 16; ++a) {
      s_p[a * 128 + wv * 32 + l]        = accv[a];
      s_p[(16 + a) * 128 + wv * 32 + l] = accq[a];
    }
    s_p[32 * 128 + wv * 32 + l] = accw;
  }
  __syncthreads();
  float* s_M = s_scr + 4224;
  {
    const int oo = t & 31;
    for (int j = t >> 5; j < 33; j += 8)
      s_M[j * 32 + oo] = s_p[j * 128 + oo] + s_p[j * 128 + 32 + oo]
                       + s_p[j * 128 + 64 + oo] + s_p[j * 128 + 96 + oo];
  }
  __syncthreads();

  const int oB = t & 31, a2B = (t >> 5) * 2;
  const int p = oB * NAc + a2B;
  const float sumR = s_M[32 * 32 + oB] + 0.2f * sumR1;
  const float sRe = sumR + EPSf, sRx = sumR + 2.f * EPSf;
  const float Mva = s_M[a2B * 32 + oB]        + 0.2f * s_m1v[p];
  const float Mvb = s_M[(a2B + 1) * 32 + oB]  + 0.2f * s_m1v[p + 1];
  const float Mqa = s_M[(16 + a2B) * 32 + oB] + 0.2f * s_m1q[p];
  const float Mqb = s_M[(17 + a2B) * 32 + oB] + 0.2f * s_m1q[p + 1];
  const float mua = Mva / sRe, mub = Mvb / sRe;
  const float sga = fmaxf((Mqa - mua * mua * sRx) / sRe, 0.f);
  const float sgb = fmaxf((Mqb - mub * mub * sRx) / sRe, 0.f);

  reinterpret_cast<float2*>(out + (size_t)site * NPc)[p >> 1] = make_float2(mua, mub);

  const float bu = beta_u[oB];
  float* s_c = s_scr;   // aliases s_p rows 0-1, consumed after the s_M barrier
  s_c[t] = (bu - 0.5f * logf(sga + EPSf)) * sumR
         + (bu - 0.5f * logf(sgb + EPSf)) * sumR;
  __syncthreads();
  if (t < NOc) {
    float c = 0.f;
#pragma unroll
    for (int k = 0; k < 8; ++k) c += s_c[t + 32 * k];
    // inv_temp (it_idx=ITERATIONS=2) = 0.01*(1-0.95^3) = 0.00142625
    const float aj = 1.f / (1.f + expf(-(0.00142625f * (beta_a[t] - c))));
    out[(size_t)NSITE * NPc + site * NOc + t] = aj;
  }
}

extern "C" void kernel_launch(void* const* d_in, const int* in_sizes, int n_in,
                              void* d_out, int out_size, void* d_ws, size_t ws_size,
                              hipStream_t stream) {
  const float* votes  = (const float*)d_in[0];
  const float* acts   = (const float*)d_in[1];
  const float* beta_a = (const float*)d_in[2];
  const float* beta_u = (const float*)d_in[3];
  float* out = (float*)d_out;
  em_fused<<<NSITE, 256, 0, stream>>>(votes, acts, beta_a, beta_u, out);
}